// Round 12
// baseline (752.703 us; speedup 1.0000x reference)
//
#include <hip/hip_runtime.h>

// ---------------- problem constants ----------------
#define G_DIM 3072
#define P_DIM 1024
#define ALPHA 0.1f

typedef __attribute__((ext_vector_type(8))) __bf16 bf16x8;
typedef __attribute__((ext_vector_type(4))) float  f32x4;

// workspace layout (bytes), peak 69.2 MB
#define GG2      ((size_t)G_DIM * G_DIM * 2)          // bf16 G×G = 18,874,368 B
#define S_OFF    ((size_t)0)
#define ST_OFF   (GG2)
#define X_OFF    ((size_t)0)
#define XBYTES   ((size_t)8192 * G_DIM * 2)           // 50,331,648 B
#define W_OFF    (XBYTES)

// ---------------- softmax: S = alpha * softmax(scores, -inf diag) ----------------
__global__ __launch_bounds__(256) void row_softmax_k(const float* __restrict__ gg,
                                                     __bf16* __restrict__ S) {
  const int i = blockIdx.x;
  const float* row = gg + (size_t)i * G_DIM * 2;  // [G][2], channel 1
  const int tid = threadIdx.x;
  const int lane = tid & 63, wave = tid >> 6;

  float v[12];
  float m = -INFINITY;
#pragma unroll
  for (int t = 0; t < 12; ++t) {
    int j = tid + t * 256;
    float x = row[2 * j + 1];
    if (j == i) x = -INFINITY;
    v[t] = x;
    m = fmaxf(m, x);
  }
#pragma unroll
  for (int o = 32; o; o >>= 1) m = fmaxf(m, __shfl_xor(m, o));
  __shared__ float red[4];
  if (lane == 0) red[wave] = m;
  __syncthreads();
  m = fmaxf(fmaxf(red[0], red[1]), fmaxf(red[2], red[3]));

  float s = 0.f;
#pragma unroll
  for (int t = 0; t < 12; ++t) {
    v[t] = __expf(v[t] - m);
    s += v[t];
  }
#pragma unroll
  for (int o = 32; o; o >>= 1) s += __shfl_xor(s, o);
  __syncthreads();
  if (lane == 0) red[wave] = s;
  __syncthreads();
  s = red[0] + red[1] + red[2] + red[3];

  const float scale = ALPHA / s;
  __bf16* out = S + (size_t)i * G_DIM;
#pragma unroll
  for (int t = 0; t < 12; ++t) {
    int j = tid + t * 256;
    out[j] = (__bf16)(v[t] * scale);
  }
}

// ---------------- bf16 transpose ----------------
__global__ void transpose_k(const __bf16* __restrict__ in, __bf16* __restrict__ out) {
  __shared__ __bf16 t[32][33];
  const int bx = blockIdx.x * 32, by = blockIdx.y * 32;
  const int tx = threadIdx.x, ty = threadIdx.y;
#pragma unroll
  for (int k = 0; k < 32; k += 8)
    t[ty + k][tx] = in[(size_t)(by + ty + k) * G_DIM + bx + tx];
  __syncthreads();
#pragma unroll
  for (int k = 0; k < 32; k += 8)
    out[(size_t)(bx + ty + k) * G_DIM + by + tx] = t[tx][ty + k];
}

// ---------------- deinterleave channels into X [8192][G] bf16, row = rr*2 + c ------
__global__ __launch_bounds__(384) void deinterleave_k(const float* __restrict__ pg,
                                                      const float* __restrict__ gg,
                                                      __bf16* __restrict__ X) {
  const int rr = blockIdx.x;  // 0..4095
  const float* src = (rr < P_DIM) ? (pg + (size_t)rr * G_DIM * 2)
                                  : (gg + (size_t)(rr - P_DIM) * G_DIM * 2);
  const int t = threadIdx.x;
  const float4* s4 = (const float4*)(src + (size_t)t * 16);
  float4 a = s4[0], b = s4[1], c = s4[2], d = s4[3];
  bf16x8 v0, v1;
  v0[0] = (__bf16)a.x; v1[0] = (__bf16)a.y;
  v0[1] = (__bf16)a.z; v1[1] = (__bf16)a.w;
  v0[2] = (__bf16)b.x; v1[2] = (__bf16)b.y;
  v0[3] = (__bf16)b.z; v1[3] = (__bf16)b.w;
  v0[4] = (__bf16)c.x; v1[4] = (__bf16)c.y;
  v0[5] = (__bf16)c.z; v1[5] = (__bf16)c.w;
  v0[6] = (__bf16)d.x; v1[6] = (__bf16)d.y;
  v0[7] = (__bf16)d.z; v1[7] = (__bf16)d.w;
  *(bf16x8*)(X + (size_t)(rr * 2) * G_DIM + t * 8)     = v0;
  *(bf16x8*)(X + (size_t)(rr * 2 + 1) * G_DIM + t * 8) = v1;
}

// ------- one staged global->LDS chunk (1 KiB), pre-swizzled source (rule #21) -------
__device__ __forceinline__ void stage1(const __bf16* __restrict__ src, size_t row0,
                                       int K, int k0, char* ldsbase, int chunk, int lane) {
  int Lb = chunk << 10;                   // wave-uniform LDS byte base
  int L  = Lb + lane * 16;                // this lane's dest byte
  int r  = L >> 7;                        // region row
  int slot = ((L >> 4) & 7) ^ (r & 7);    // inverse swizzle on SOURCE
  const __bf16* g = src + (row0 + (size_t)r) * (size_t)K + (size_t)(k0 + slot * 8);
  __builtin_amdgcn_global_load_lds((const __attribute__((address_space(1))) void*)g,
                                   (__attribute__((address_space(3))) void*)(ldsbase + Lb),
                                   16, 0, 0);
}

#define MFMA16(a, b, c) __builtin_amdgcn_mfma_f32_16x16x32_bf16((a), (b), (c), 0, 0, 0)
#define LDS_RD(base, row, xx) (*(const bf16x8*)((base) + (size_t)(row) * 128 + (xx)))
#define LGKM0()  asm volatile("s_waitcnt lgkmcnt(0)" ::: "memory")
#define VM3()    asm volatile("s_waitcnt vmcnt(3)" ::: "memory")
#define VM0()    asm volatile("s_waitcnt vmcnt(0)" ::: "memory")
#define BAR()    __builtin_amdgcn_s_barrier()
#define PRIO(x)  __builtin_amdgcn_s_setprio(x)
#define FENCE()  asm volatile("" ::: "memory")

// ======== PROPAGATE: 256x192 NT GEMM, A direct-to-registers, B LDS ring-3 ========
// Logic identical to R10/R11 (correctness-proven twice). Fix for the 128-VGPR spill:
// LDS padded to 96 KiB so only ONE block fits per CU -> max occupancy is 2 waves/EU
// regardless of VGPR count -> allocator has no incentive to cap at 128 -> the ~230
// live regs (3x8 A-sets + 96 acc) allocate spill-free.
// 8 waves (2M x 4N), wave tile 128x48, acc[8][3]. B ring uses first 72 KiB.
// out f32 paired = acc + 0.9*orig f32 (X row = rr*2+c)
__global__ __launch_bounds__(512, 2)
void gemm_adir(const __bf16* __restrict__ A,
               const __bf16* __restrict__ B,
               void* __restrict__ C,
               const float* __restrict__ pgin,
               const float* __restrict__ ggin,
               int M, int N, int K) {
  __shared__ char lds[98304];   // 3 x 24 KiB B ring + 24 KiB occupancy pad (1 block/CU)

  const int tid = threadIdx.x;
  const int wave = tid >> 6, lane = tid & 63;
  const int wm = wave >> 2, wn = wave & 3;   // 2M x 4N
  const int lr = lane & 15, g4 = lane >> 4;

  const size_t arow0 = (size_t)blockIdx.x * 256;   // bx = M-tile
  const size_t brow0 = (size_t)blockIdx.y * 192;

  f32x4 acc[8][3] = {};
  const int NT = K / 64;   // 48, divisible by 3

  const int b3w = wave * 3;
  const int x0 = ((g4) ^ (lr & 7)) * 16;
  const int x1 = ((4 + g4) ^ (lr & 7)) * 16;

  // per-thread A base: row = arow0 + wm*128 + lr (+ mf*16), k stepped by tile
  const __bf16* Arow = A + (arow0 + (size_t)(wm * 128 + lr)) * (size_t)K;
  const size_t mfstep = (size_t)16 * K;

  bf16x8 R0[8], R1[8], R2[8];

  // prologue: stage B0(slot0), B1(slot1); load A_0 ks0->R0, ks1->R1; drain; barrier
  stage1(B, brow0, K, 0,  lds,         b3w,     lane);
  stage1(B, brow0, K, 0,  lds,         b3w + 1, lane);
  stage1(B, brow0, K, 0,  lds,         b3w + 2, lane);
  stage1(B, brow0, K, 64, lds + 24576, b3w,     lane);
  stage1(B, brow0, K, 64, lds + 24576, b3w + 1, lane);
  stage1(B, brow0, K, 64, lds + 24576, b3w + 2, lane);
#pragma unroll
  for (int mf = 0; mf < 8; ++mf)
    R0[mf] = *(const bf16x8*)(Arow + mf * mfstep + g4 * 8);
#pragma unroll
  for (int mf = 0; mf < 8; ++mf)
    R1[mf] = *(const bf16x8*)(Arow + mf * mfstep + 32 + g4 * 8);
  VM0();
  BAR();

  // tile body: SA = this tile's ks0 regs, SB = ks1 regs, SC = receives next ks0
#define TILE(T, SA, SB, SC, RSLOT, WSLOT)                                        \
  {                                                                              \
    FENCE();                                                                     \
    if ((T) + 2 < NT) {                                                          \
      char* Bst = lds + (WSLOT) * 24576;                                         \
      stage1(B, brow0, K, ((T) + 2) * 64, Bst, b3w,     lane);                   \
      stage1(B, brow0, K, ((T) + 2) * 64, Bst, b3w + 1, lane);                   \
      stage1(B, brow0, K, ((T) + 2) * 64, Bst, b3w + 2, lane);                   \
    }                                                                            \
    FENCE();                                                                     \
    if ((T) + 1 < NT) {                                                          \
      _Pragma("unroll")                                                          \
      for (int mf = 0; mf < 8; ++mf)                                             \
        SC[mf] = *(const bf16x8*)(Arow + mf * mfstep +                           \
                                  (size_t)(((T) + 1) * 64) + g4 * 8);            \
    }                                                                            \
    {                                                                            \
      char* Bb = lds + (RSLOT) * 24576;                                          \
      bf16x8 bv0[3];                                                             \
      _Pragma("unroll")                                                          \
      for (int nf = 0; nf < 3; ++nf)                                             \
        bv0[nf] = LDS_RD(Bb, wn * 48 + nf * 16 + lr, x0);                        \
      PRIO(1);                                                                   \
      _Pragma("unroll")                                                          \
      for (int mf = 0; mf < 8; ++mf)                                             \
        _Pragma("unroll")                                                        \
        for (int nf = 0; nf < 3; ++nf)                                           \
          acc[mf][nf] = MFMA16(SA[mf], bv0[nf], acc[mf][nf]);                    \
      PRIO(0);                                                                   \
      if ((T) + 1 < NT) {                                                        \
        _Pragma("unroll")                                                        \
        for (int mf = 0; mf < 8; ++mf)                                           \
          SA[mf] = *(const bf16x8*)(Arow + mf * mfstep +                         \
                                    (size_t)(((T) + 1) * 64) + 32 + g4 * 8);     \
      }                                                                          \
      bf16x8 bv1[3];                                                             \
      _Pragma("unroll")                                                          \
      for (int nf = 0; nf < 3; ++nf)                                             \
        bv1[nf] = LDS_RD(Bb, wn * 48 + nf * 16 + lr, x1);                        \
      PRIO(1);                                                                   \
      _Pragma("unroll")                                                          \
      for (int mf = 0; mf < 8; ++mf)                                             \
        _Pragma("unroll")                                                        \
        for (int nf = 0; nf < 3; ++nf)                                           \
          acc[mf][nf] = MFMA16(SB[mf], bv1[nf], acc[mf][nf]);                    \
      PRIO(0);                                                                   \
    }                                                                            \
    LGKM0();                                                                     \
    BAR();                                                                       \
  }

  for (int t = 0; t < NT; t += 3) {
    TILE(t,     R0, R1, R2, 0, 2);
    TILE(t + 1, R2, R0, R1, 1, 0);
    TILE(t + 2, R1, R2, R0, 2, 1);
  }
#undef TILE

  // epilogue — C/D layout: col = lane&15, row = (lane>>4)*4 + reg
  const int r0 = (int)arow0 + wm * 128;
  const int c0 = (int)brow0 + wn * 48;
#pragma unroll
  for (int mf = 0; mf < 8; ++mf) {
#pragma unroll
    for (int nf = 0; nf < 3; ++nf) {
      const int col = c0 + nf * 16 + lr;
#pragma unroll
      for (int jp = 0; jp < 2; ++jp) {
        const int row = r0 + mf * 16 + g4 * 4 + jp * 2;  // even
        const int rr = row >> 1;
        const size_t base = (size_t)rr * G_DIM * 2 + (size_t)col * 2;
        const float* src = (rr < P_DIM) ? (pgin + base)
                                        : (ggin + base - (size_t)P_DIM * G_DIM * 2);
        float2 sv = *(const float2*)src;
        float2 ov;
        ov.x = acc[mf][nf][jp * 2]     + 0.9f * sv.x;
        ov.y = acc[mf][nf][jp * 2 + 1] + 0.9f * sv.y;
        *(float2*)((float*)C + base) = ov;
      }
    }
  }
  (void)M;
}

// ======== W-GEMM: 192x192 NT, one barrier / K-tile, A dbuf + B ring-3 (R8) ========
// grid 16x16 = 256 blocks = exactly 1 CU round. MF=6: wave tile 96x48.
// C bf16 = 0.9*(acc + e0[i,j])   (W = 0.9*(S^2 + S))
__global__ __launch_bounds__(512, 2) void gemmW(const __bf16* __restrict__ A,
                                                const __bf16* __restrict__ B,
                                                __bf16* __restrict__ C,
                                                const __bf16* __restrict__ e0,
                                                int N, int K) {
  constexpr int MF     = 6;
  constexpr int BM     = MF * 32;       // 192
  constexpr int ABYTES = BM * 128;      // 24576
  constexpr int ACH    = BM / 64;       // 3
  __shared__ char lds[2 * ABYTES + 3 * 24576];

  const int tid = threadIdx.x;
  const int wave = tid >> 6, lane = tid & 63;
  const int wm = wave >> 2, wn = wave & 3;   // 2M x 4N
  const int lr = lane & 15, g4 = lane >> 4;

  const size_t arow0 = (size_t)blockIdx.x * BM;
  const size_t brow0 = (size_t)blockIdx.y * 192;

  f32x4 acc[MF][3] = {};
  const int NT = K / 64;

  const int x0 = ((g4) ^ (lr & 7)) * 16;
  const int x1 = ((4 + g4) ^ (lr & 7)) * 16;
  const int arbase = wm * (MF * 16);

  {
    char* A0 = lds;
    char* B0 = lds + 2 * ABYTES;
    char* B1 = B0 + 24576;
#pragma unroll
    for (int q = 0; q < ACH; ++q) stage1(A, arow0, K, 0,  A0, wave * ACH + q, lane);
#pragma unroll
    for (int q = 0; q < 3; ++q)   stage1(B, brow0, K, 0,  B0, wave * 3 + q, lane);
#pragma unroll
    for (int q = 0; q < 3; ++q)   stage1(B, brow0, K, 64, B1, wave * 3 + q, lane);
  }

  for (int t = 0; t < NT; ++t) {
    char* Abuf = lds + (t & 1) * ABYTES;
    char* Anxt = lds + ((t + 1) & 1) * ABYTES;
    char* Bbuf = lds + 2 * ABYTES + (t % 3) * 24576;
    char* Bst  = lds + 2 * ABYTES + ((t + 2) % 3) * 24576;

    if (t == NT - 1) VM0(); else VM3();
    BAR();
    FENCE();

    if (t + 1 < NT) {
#pragma unroll
      for (int q = 0; q < ACH; ++q)
        stage1(A, arow0, K, (t + 1) * 64, Anxt, wave * ACH + q, lane);
    }
    if (t + 2 < NT) {
#pragma unroll
      for (int q = 0; q < 3; ++q)
        stage1(B, brow0, K, (t + 2) * 64, Bst, wave * 3 + q, lane);
    }

    bf16x8 av[MF][2], bv[3][2];
#pragma unroll
    for (int mf = 0; mf < MF; ++mf) {
      av[mf][0] = LDS_RD(Abuf, arbase + mf * 16 + lr, x0);
      av[mf][1] = LDS_RD(Abuf, arbase + mf * 16 + lr, x1);
    }
#pragma unroll
    for (int nf = 0; nf < 3; ++nf) {
      bv[nf][0] = LDS_RD(Bbuf, wn * 48 + nf * 16 + lr, x0);
      bv[nf][1] = LDS_RD(Bbuf, wn * 48 + nf * 16 + lr, x1);
    }
    PRIO(1);
#pragma unroll
    for (int mf = 0; mf < MF; ++mf)
#pragma unroll
      for (int nf = 0; nf < 3; ++nf)
#pragma unroll
        for (int ks = 0; ks < 2; ++ks)
          acc[mf][nf] = MFMA16(av[mf][ks], bv[nf][ks], acc[mf][nf]);
    PRIO(0);
    LGKM0();
  }

  const int r0 = (int)arow0 + arbase;
  const int c0 = (int)brow0 + wn * 48;
#pragma unroll
  for (int mf = 0; mf < MF; ++mf) {
#pragma unroll
    for (int nf = 0; nf < 3; ++nf) {
      const int col = c0 + nf * 16 + lr;
#pragma unroll
      for (int jj = 0; jj < 4; ++jj) {
        const int row = r0 + mf * 16 + g4 * 4 + jj;
        float w = 0.9f * (acc[mf][nf][jj] + (float)e0[(size_t)row * N + col]);
        C[(size_t)row * N + col] = (__bf16)w;
      }
    }
  }
}

// ---------------- launch ----------------
extern "C" void kernel_launch(void* const* d_in, const int* in_sizes, int n_in,
                              void* d_out, int out_size, void* d_ws, size_t ws_size,
                              hipStream_t stream) {
  const float* pg = (const float*)d_in[0];  // [P,G,2] f32
  const float* gg = (const float*)d_in[1];  // [G,G,2] f32
  float* out = (float*)d_out;

  char* ws = (char*)d_ws;
  __bf16* S  = (__bf16*)(ws + S_OFF);
  __bf16* St = (__bf16*)(ws + ST_OFF);
  __bf16* W  = (__bf16*)(ws + W_OFF);
  __bf16* X  = (__bf16*)(ws + X_OFF);    // overlays S/St (dead by then)

  // 1. S = alpha * softmax(gg[:,:,1], -inf diag)      [G,G] bf16
  row_softmax_k<<<G_DIM, 256, 0, stream>>>(gg, S);
  // 2. St = S^T
  transpose_k<<<dim3(96, 96), dim3(32, 8), 0, stream>>>(S, St);
  // 3. W = 0.9*(S*S + S)   (192x192 tile -> 256 blocks = exactly 1 CU round)
  gemmW<<<dim3(16, 16), 512, 0, stream>>>(S, St, W, S, G_DIM, G_DIM);
  // 4. X[rr*2+c][g] = bf16(src[rr][g][c])
  deinterleave_k<<<4096, 384, 0, stream>>>(pg, gg, X);
  // 5. out = X * W^T + 0.9 * X_f32   (256x192, A-direct registers + B ring-3)
  gemm_adir<<<dim3(32, 16), 512, 0, stream>>>(X, W, out, pg, gg, 8192, G_DIM, G_DIM);
  (void)in_sizes; (void)n_in; (void)out_size; (void)ws_size;
}

// Round 13
// 249.532 us; speedup vs baseline: 3.0165x; 3.0165x over previous
//
#include <hip/hip_runtime.h>

// ---------------- problem constants ----------------
#define G_DIM 3072
#define P_DIM 1024
#define ALPHA 0.1f

typedef __attribute__((ext_vector_type(8))) __bf16 bf16x8;
typedef __attribute__((ext_vector_type(4))) float  f32x4;

// workspace layout (bytes), peak 69.2 MB
#define GG2      ((size_t)G_DIM * G_DIM * 2)          // bf16 G×G = 18,874,368 B
#define S_OFF    ((size_t)0)
#define ST_OFF   (GG2)
#define X_OFF    ((size_t)0)
#define XBYTES   ((size_t)8192 * G_DIM * 2)           // 50,331,648 B
#define W_OFF    (XBYTES)

// ---------------- softmax: S = alpha * softmax(scores, -inf diag) ----------------
__global__ __launch_bounds__(256) void row_softmax_k(const float* __restrict__ gg,
                                                     __bf16* __restrict__ S) {
  const int i = blockIdx.x;
  const float* row = gg + (size_t)i * G_DIM * 2;  // [G][2], channel 1
  const int tid = threadIdx.x;
  const int lane = tid & 63, wave = tid >> 6;

  float v[12];
  float m = -INFINITY;
#pragma unroll
  for (int t = 0; t < 12; ++t) {
    int j = tid + t * 256;
    float x = row[2 * j + 1];
    if (j == i) x = -INFINITY;
    v[t] = x;
    m = fmaxf(m, x);
  }
#pragma unroll
  for (int o = 32; o; o >>= 1) m = fmaxf(m, __shfl_xor(m, o));
  __shared__ float red[4];
  if (lane == 0) red[wave] = m;
  __syncthreads();
  m = fmaxf(fmaxf(red[0], red[1]), fmaxf(red[2], red[3]));

  float s = 0.f;
#pragma unroll
  for (int t = 0; t < 12; ++t) {
    v[t] = __expf(v[t] - m);
    s += v[t];
  }
#pragma unroll
  for (int o = 32; o; o >>= 1) s += __shfl_xor(s, o);
  __syncthreads();
  if (lane == 0) red[wave] = s;
  __syncthreads();
  s = red[0] + red[1] + red[2] + red[3];

  const float scale = ALPHA / s;
  __bf16* out = S + (size_t)i * G_DIM;
#pragma unroll
  for (int t = 0; t < 12; ++t) {
    int j = tid + t * 256;
    out[j] = (__bf16)(v[t] * scale);
  }
}

// ---------------- bf16 transpose ----------------
__global__ void transpose_k(const __bf16* __restrict__ in, __bf16* __restrict__ out) {
  __shared__ __bf16 t[32][33];
  const int bx = blockIdx.x * 32, by = blockIdx.y * 32;
  const int tx = threadIdx.x, ty = threadIdx.y;
#pragma unroll
  for (int k = 0; k < 32; k += 8)
    t[ty + k][tx] = in[(size_t)(by + ty + k) * G_DIM + bx + tx];
  __syncthreads();
#pragma unroll
  for (int k = 0; k < 32; k += 8)
    out[(size_t)(bx + ty + k) * G_DIM + by + tx] = t[tx][ty + k];
}

// ---------------- deinterleave channels into X [8192][G] bf16, row = rr*2 + c ------
__global__ __launch_bounds__(384) void deinterleave_k(const float* __restrict__ pg,
                                                      const float* __restrict__ gg,
                                                      __bf16* __restrict__ X) {
  const int rr = blockIdx.x;  // 0..4095
  const float* src = (rr < P_DIM) ? (pg + (size_t)rr * G_DIM * 2)
                                  : (gg + (size_t)(rr - P_DIM) * G_DIM * 2);
  const int t = threadIdx.x;
  const float4* s4 = (const float4*)(src + (size_t)t * 16);
  float4 a = s4[0], b = s4[1], c = s4[2], d = s4[3];
  bf16x8 v0, v1;
  v0[0] = (__bf16)a.x; v1[0] = (__bf16)a.y;
  v0[1] = (__bf16)a.z; v1[1] = (__bf16)a.w;
  v0[2] = (__bf16)b.x; v1[2] = (__bf16)b.y;
  v0[3] = (__bf16)b.z; v1[3] = (__bf16)b.w;
  v0[4] = (__bf16)c.x; v1[4] = (__bf16)c.y;
  v0[5] = (__bf16)c.z; v1[5] = (__bf16)c.w;
  v0[6] = (__bf16)d.x; v1[6] = (__bf16)d.y;
  v0[7] = (__bf16)d.z; v1[7] = (__bf16)d.w;
  *(bf16x8*)(X + (size_t)(rr * 2) * G_DIM + t * 8)     = v0;
  *(bf16x8*)(X + (size_t)(rr * 2 + 1) * G_DIM + t * 8) = v1;
}

// ------- one staged global->LDS chunk (1 KiB), pre-swizzled source (rule #21) -------
__device__ __forceinline__ void stage1(const __bf16* __restrict__ src, size_t row0,
                                       int K, int k0, char* ldsbase, int chunk, int lane) {
  int Lb = chunk << 10;                   // wave-uniform LDS byte base
  int L  = Lb + lane * 16;                // this lane's dest byte
  int r  = L >> 7;                        // region row
  int slot = ((L >> 4) & 7) ^ (r & 7);    // inverse swizzle on SOURCE
  const __bf16* g = src + (row0 + (size_t)r) * (size_t)K + (size_t)(k0 + slot * 8);
  __builtin_amdgcn_global_load_lds((const __attribute__((address_space(1))) void*)g,
                                   (__attribute__((address_space(3))) void*)(ldsbase + Lb),
                                   16, 0, 0);
}

#define MFMA16(a, b, c) __builtin_amdgcn_mfma_f32_16x16x32_bf16((a), (b), (c), 0, 0, 0)
#define LDS_RD(base, row, xx) (*(const bf16x8*)((base) + (size_t)(row) * 128 + (xx)))
#define LGKM0()  asm volatile("s_waitcnt lgkmcnt(0)" ::: "memory")
#define VM3()    asm volatile("s_waitcnt vmcnt(3)" ::: "memory")
#define VM0()    asm volatile("s_waitcnt vmcnt(0)" ::: "memory")
#define BAR()    __builtin_amdgcn_s_barrier()
#define PRIO(x)  __builtin_amdgcn_s_setprio(x)
#define FENCE()  asm volatile("" ::: "memory")

// ======== PROPAGATE: 256x192 NT GEMM, 3 phases / K-tile (R7/R9 proven, 161 us) ========
// 8 waves (2M x 4N), wave tile 128x48, acc[8][3]. LDS: 2 bufs x (A 32K | B 24K).
// out f32 paired = acc + 0.9*orig f32 (propagate, X row = rr*2+c)
__global__ __launch_bounds__(512, 2) void gemm3p(const __bf16* __restrict__ A,
                                                 const __bf16* __restrict__ B,
                                                 void* __restrict__ C,
                                                 const float* __restrict__ pgin,
                                                 const float* __restrict__ ggin,
                                                 int M, int N, int K) {
  __shared__ char lds[114688];   // 2 x (32 KiB A + 24 KiB B)

  const int tid = threadIdx.x;
  const int wave = tid >> 6, lane = tid & 63;
  const int wm = wave >> 2, wn = wave & 3;   // 2M x 4N
  const int lr = lane & 15, g4 = lane >> 4;

  const size_t arow0 = (size_t)blockIdx.x * 256;   // bx = M-tile
  const size_t brow0 = (size_t)blockIdx.y * 192;

  f32x4 acc[8][3] = {};
  const int NT = K / 64;

  const int a2w = wave * 2;
  const int b3w = wave * 3;
  const int x0 = ((g4) ^ (lr & 7)) * 16;
  const int x1 = ((4 + g4) ^ (lr & 7)) * 16;

  // prologue: tile0 {A0,A1,B} + tile1 {B}
  {
    char* b0 = lds;
    char* b1 = lds + 57344;
    stage1(A, arow0,       K, 0,  b0,         a2w, lane);
    stage1(A, arow0,       K, 0,  b0,         a2w + 1, lane);
    stage1(A, arow0 + 128, K, 0,  b0 + 16384, a2w, lane);
    stage1(A, arow0 + 128, K, 0,  b0 + 16384, a2w + 1, lane);
    stage1(B, brow0,       K, 0,  b0 + 32768, b3w, lane);
    stage1(B, brow0,       K, 0,  b0 + 32768, b3w + 1, lane);
    stage1(B, brow0,       K, 0,  b0 + 32768, b3w + 2, lane);
    stage1(B, brow0,       K, 64, b1 + 32768, b3w, lane);
    stage1(B, brow0,       K, 64, b1 + 32768, b3w + 1, lane);
    stage1(B, brow0,       K, 64, b1 + 32768, b3w + 2, lane);
  }
  VM3();
  BAR();

  for (int t = 0; t < NT; ++t) {
    char* buf = lds + (t & 1) * 57344;
    char* nxt = lds + ((t + 1) & 1) * 57344;
    char* Ab = buf + wm * 16384;
    char* Bb = buf + 32768;
    const int kn = (t + 1) * 64;
    const int k2 = (t + 2) * 64;
    const bool pa = (t + 1) < NT;
    const bool pb = (t + 2) < NT;

    bf16x8 alo[4][2], ahi[4][2], b01[2][2], b2[2];

    // ---- ph1: stage A0_{t+1}; read alo + b01; MFMA alo x b01 (16) ----
    if (pa) {
      stage1(A, arow0, K, kn, nxt, a2w, lane);
      stage1(A, arow0, K, kn, nxt, a2w + 1, lane);
    }
#pragma unroll
    for (int mf = 0; mf < 4; ++mf) {
      alo[mf][0] = LDS_RD(Ab, mf * 16 + lr, x0);
      alo[mf][1] = LDS_RD(Ab, mf * 16 + lr, x1);
    }
#pragma unroll
    for (int nf = 0; nf < 2; ++nf) {
      b01[nf][0] = LDS_RD(Bb, wn * 48 + nf * 16 + lr, x0);
      b01[nf][1] = LDS_RD(Bb, wn * 48 + nf * 16 + lr, x1);
    }
    PRIO(1);
#pragma unroll
    for (int mf = 0; mf < 4; ++mf)
#pragma unroll
      for (int nf = 0; nf < 2; ++nf)
#pragma unroll
        for (int ks = 0; ks < 2; ++ks)
          acc[mf][nf] = MFMA16(alo[mf][ks], b01[nf][ks], acc[mf][nf]);
    PRIO(0);

    // ---- ph2: stage A1_{t+1}; read ahi + b2; MFMA (alo,ahi) x b2 (16) ----
    if (pa) {
      stage1(A, arow0 + 128, K, kn, nxt + 16384, a2w, lane);
      stage1(A, arow0 + 128, K, kn, nxt + 16384, a2w + 1, lane);
    }
#pragma unroll
    for (int mf = 0; mf < 4; ++mf) {
      ahi[mf][0] = LDS_RD(Ab, 64 + mf * 16 + lr, x0);
      ahi[mf][1] = LDS_RD(Ab, 64 + mf * 16 + lr, x1);
    }
    b2[0] = LDS_RD(Bb, wn * 48 + 32 + lr, x0);
    b2[1] = LDS_RD(Bb, wn * 48 + 32 + lr, x1);
    PRIO(1);
#pragma unroll
    for (int mf = 0; mf < 4; ++mf)
#pragma unroll
      for (int ks = 0; ks < 2; ++ks) {
        acc[mf][2]     = MFMA16(alo[mf][ks], b2[ks], acc[mf][2]);
        acc[4 + mf][2] = MFMA16(ahi[mf][ks], b2[ks], acc[4 + mf][2]);
      }
    PRIO(0);
    LGKM0();
    BAR();     // BAR#1: safe to overwrite buf.B

    // ---- ph3: stage B_{t+2} -> buf; MFMA ahi x b01 (16); gate; BAR#2 ----
    if (pb) {
      stage1(B, brow0, K, k2, Bb, b3w, lane);
      stage1(B, brow0, K, k2, Bb, b3w + 1, lane);
      stage1(B, brow0, K, k2, Bb, b3w + 2, lane);
    }
    PRIO(1);
#pragma unroll
    for (int mf = 0; mf < 4; ++mf)
#pragma unroll
      for (int nf = 0; nf < 2; ++nf)
#pragma unroll
        for (int ks = 0; ks < 2; ++ks)
          acc[4 + mf][nf] = MFMA16(ahi[mf][ks], b01[nf][ks], acc[4 + mf][nf]);
    PRIO(0);
    if (t >= NT - 2) VM0(); else VM3();
    BAR();     // BAR#2
  }

  // epilogue — C/D layout: col = lane&15, row = (lane>>4)*4 + reg
  const int r0 = (int)arow0 + wm * 128;
  const int c0 = (int)brow0 + wn * 48;
#pragma unroll
  for (int mf = 0; mf < 8; ++mf) {
#pragma unroll
    for (int nf = 0; nf < 3; ++nf) {
      const int col = c0 + nf * 16 + lr;
#pragma unroll
      for (int jp = 0; jp < 2; ++jp) {
        const int row = r0 + mf * 16 + g4 * 4 + jp * 2;  // even
        const int rr = row >> 1;
        const size_t base = (size_t)rr * G_DIM * 2 + (size_t)col * 2;
        const float* src = (rr < P_DIM) ? (pgin + base)
                                        : (ggin + base - (size_t)P_DIM * G_DIM * 2);
        float2 sv = *(const float2*)src;
        float2 ov;
        ov.x = acc[mf][nf][jp * 2]     + 0.9f * sv.x;
        ov.y = acc[mf][nf][jp * 2 + 1] + 0.9f * sv.y;
        *(float2*)((float*)C + base) = ov;
      }
    }
  }
  (void)M;
}

// ======== W-GEMM: 192x192 NT, one barrier / K-tile, A dbuf + B ring-3 (R8) ========
// grid 16x16 = 256 blocks = exactly 1 CU round. MF=6: wave tile 96x48.
// C bf16 = 0.9*(acc + e0[i,j])   (W = 0.9*(S^2 + S))
__global__ __launch_bounds__(512, 2) void gemmW(const __bf16* __restrict__ A,
                                                const __bf16* __restrict__ B,
                                                __bf16* __restrict__ C,
                                                const __bf16* __restrict__ e0,
                                                int N, int K) {
  constexpr int MF     = 6;
  constexpr int BM     = MF * 32;       // 192
  constexpr int ABYTES = BM * 128;      // 24576
  constexpr int ACH    = BM / 64;       // 3
  __shared__ char lds[2 * ABYTES + 3 * 24576];

  const int tid = threadIdx.x;
  const int wave = tid >> 6, lane = tid & 63;
  const int wm = wave >> 2, wn = wave & 3;   // 2M x 4N
  const int lr = lane & 15, g4 = lane >> 4;

  const size_t arow0 = (size_t)blockIdx.x * BM;
  const size_t brow0 = (size_t)blockIdx.y * 192;

  f32x4 acc[MF][3] = {};
  const int NT = K / 64;

  const int x0 = ((g4) ^ (lr & 7)) * 16;
  const int x1 = ((4 + g4) ^ (lr & 7)) * 16;
  const int arbase = wm * (MF * 16);

  {
    char* A0 = lds;
    char* B0 = lds + 2 * ABYTES;
    char* B1 = B0 + 24576;
#pragma unroll
    for (int q = 0; q < ACH; ++q) stage1(A, arow0, K, 0,  A0, wave * ACH + q, lane);
#pragma unroll
    for (int q = 0; q < 3; ++q)   stage1(B, brow0, K, 0,  B0, wave * 3 + q, lane);
#pragma unroll
    for (int q = 0; q < 3; ++q)   stage1(B, brow0, K, 64, B1, wave * 3 + q, lane);
  }

  for (int t = 0; t < NT; ++t) {
    char* Abuf = lds + (t & 1) * ABYTES;
    char* Anxt = lds + ((t + 1) & 1) * ABYTES;
    char* Bbuf = lds + 2 * ABYTES + (t % 3) * 24576;
    char* Bst  = lds + 2 * ABYTES + ((t + 2) % 3) * 24576;

    if (t == NT - 1) VM0(); else VM3();
    BAR();
    FENCE();

    if (t + 1 < NT) {
#pragma unroll
      for (int q = 0; q < ACH; ++q)
        stage1(A, arow0, K, (t + 1) * 64, Anxt, wave * ACH + q, lane);
    }
    if (t + 2 < NT) {
#pragma unroll
      for (int q = 0; q < 3; ++q)
        stage1(B, brow0, K, (t + 2) * 64, Bst, wave * 3 + q, lane);
    }

    bf16x8 av[MF][2], bv[3][2];
#pragma unroll
    for (int mf = 0; mf < MF; ++mf) {
      av[mf][0] = LDS_RD(Abuf, arbase + mf * 16 + lr, x0);
      av[mf][1] = LDS_RD(Abuf, arbase + mf * 16 + lr, x1);
    }
#pragma unroll
    for (int nf = 0; nf < 3; ++nf) {
      bv[nf][0] = LDS_RD(Bbuf, wn * 48 + nf * 16 + lr, x0);
      bv[nf][1] = LDS_RD(Bbuf, wn * 48 + nf * 16 + lr, x1);
    }
    PRIO(1);
#pragma unroll
    for (int mf = 0; mf < MF; ++mf)
#pragma unroll
      for (int nf = 0; nf < 3; ++nf)
#pragma unroll
        for (int ks = 0; ks < 2; ++ks)
          acc[mf][nf] = MFMA16(av[mf][ks], bv[nf][ks], acc[mf][nf]);
    PRIO(0);
    LGKM0();
  }

  const int r0 = (int)arow0 + arbase;
  const int c0 = (int)brow0 + wn * 48;
#pragma unroll
  for (int mf = 0; mf < MF; ++mf) {
#pragma unroll
    for (int nf = 0; nf < 3; ++nf) {
      const int col = c0 + nf * 16 + lr;
#pragma unroll
      for (int jj = 0; jj < 4; ++jj) {
        const int row = r0 + mf * 16 + g4 * 4 + jj;
        float w = 0.9f * (acc[mf][nf][jj] + (float)e0[(size_t)row * N + col]);
        C[(size_t)row * N + col] = (__bf16)w;
      }
    }
  }
}

// ---------------- launch ----------------
extern "C" void kernel_launch(void* const* d_in, const int* in_sizes, int n_in,
                              void* d_out, int out_size, void* d_ws, size_t ws_size,
                              hipStream_t stream) {
  const float* pg = (const float*)d_in[0];  // [P,G,2] f32
  const float* gg = (const float*)d_in[1];  // [G,G,2] f32
  float* out = (float*)d_out;

  char* ws = (char*)d_ws;
  __bf16* S  = (__bf16*)(ws + S_OFF);
  __bf16* St = (__bf16*)(ws + ST_OFF);
  __bf16* W  = (__bf16*)(ws + W_OFF);
  __bf16* X  = (__bf16*)(ws + X_OFF);    // overlays S/St (dead by then)

  // 1. S = alpha * softmax(gg[:,:,1], -inf diag)      [G,G] bf16
  row_softmax_k<<<G_DIM, 256, 0, stream>>>(gg, S);
  // 2. St = S^T
  transpose_k<<<dim3(96, 96), dim3(32, 8), 0, stream>>>(S, St);
  // 3. W = 0.9*(S*S + S)   (192x192 tile -> 256 blocks = exactly 1 CU round)
  gemmW<<<dim3(16, 16), 512, 0, stream>>>(S, St, W, S, G_DIM, G_DIM);
  // 4. X[rr*2+c][g] = bf16(src[rr][g][c])
  deinterleave_k<<<4096, 384, 0, stream>>>(pg, gg, X);
  // 5. out = X * W^T + 0.9 * X_f32   (256x192 tile, 3-phase R7 schedule)
  gemm3p<<<dim3(32, 16), 512, 0, stream>>>(X, W, out, pg, gg, 8192, G_DIM, G_DIM);
  (void)in_sizes; (void)n_in; (void)out_size; (void)ws_size;
}

// Round 14
// 241.511 us; speedup vs baseline: 3.1166x; 1.0332x over previous
//
#include <hip/hip_runtime.h>

// ---------------- problem constants ----------------
#define G_DIM 3072
#define P_DIM 1024
#define ALPHA 0.1f

typedef __attribute__((ext_vector_type(8))) __bf16 bf16x8;
typedef __attribute__((ext_vector_type(4))) float  f32x4;

// ---- memory plan ----
// ws  (69.2 MB used): X = [0, 50.3M)  bf16 [8192][3072], row = rr*2 + c
//                     W = [50.3M, 69.2M) bf16 [3072][3072]
// d_out (100.7 MB) doubles as scratch BEFORE the propagate (which overwrites
// every output element): S = d_out[0,18.9M), St = d_out[18.9M,37.7M).
#define GG2      ((size_t)G_DIM * G_DIM * 2)          // bf16 G×G = 18,874,368 B
#define XBYTES   ((size_t)8192 * G_DIM * 2)           // 50,331,648 B

// ---- softmax + gg-channel deinterleave fused ----
// S = alpha * softmax(gg[:,:,1], -inf diag)  (S from raw f32 — precision unchanged)
// X rows 2048+2i / 2049+2i = bf16(gg[i][:][0]) / bf16(gg[i][:][1])  (raw scores)
__global__ __launch_bounds__(256) void row_softmax_k(const float* __restrict__ gg,
                                                     __bf16* __restrict__ S,
                                                     __bf16* __restrict__ X) {
  const int i = blockIdx.x;
  const float* row = gg + (size_t)i * G_DIM * 2;  // [G][2]
  const int tid = threadIdx.x;
  const int lane = tid & 63, wave = tid >> 6;

  float2 p[12];
  float v[12];
  float m = -INFINITY;
#pragma unroll
  for (int t = 0; t < 12; ++t) {
    int j = tid + t * 256;
    p[t] = ((const float2*)row)[j];
    float x = p[t].y;
    if (j == i) x = -INFINITY;
    v[t] = x;
    m = fmaxf(m, x);
  }

  // write X gg-rows (raw scores, both channels) — coalesced 2B x 256/wavefront
  {
    __bf16* x0 = X + (size_t)(2048 + 2 * i) * G_DIM;
    __bf16* x1 = x0 + G_DIM;
#pragma unroll
    for (int t = 0; t < 12; ++t) {
      int j = tid + t * 256;
      x0[j] = (__bf16)p[t].x;
      x1[j] = (__bf16)p[t].y;
    }
  }

#pragma unroll
  for (int o = 32; o; o >>= 1) m = fmaxf(m, __shfl_xor(m, o));
  __shared__ float red[4];
  if (lane == 0) red[wave] = m;
  __syncthreads();
  m = fmaxf(fmaxf(red[0], red[1]), fmaxf(red[2], red[3]));

  float s = 0.f;
#pragma unroll
  for (int t = 0; t < 12; ++t) {
    v[t] = __expf(v[t] - m);   // exp(-inf - m) = 0 handles diag
    s += v[t];
  }
#pragma unroll
  for (int o = 32; o; o >>= 1) s += __shfl_xor(s, o);
  __syncthreads();
  if (lane == 0) red[wave] = s;
  __syncthreads();
  s = red[0] + red[1] + red[2] + red[3];

  const float scale = ALPHA / s;
  __bf16* out = S + (size_t)i * G_DIM;
#pragma unroll
  for (int t = 0; t < 12; ++t) {
    int j = tid + t * 256;
    out[j] = (__bf16)(v[t] * scale);
  }
}

// ---------------- bf16 transpose ----------------
__global__ void transpose_k(const __bf16* __restrict__ in, __bf16* __restrict__ out) {
  __shared__ __bf16 t[32][33];
  const int bx = blockIdx.x * 32, by = blockIdx.y * 32;
  const int tx = threadIdx.x, ty = threadIdx.y;
#pragma unroll
  for (int k = 0; k < 32; k += 8)
    t[ty + k][tx] = in[(size_t)(by + ty + k) * G_DIM + bx + tx];
  __syncthreads();
#pragma unroll
  for (int k = 0; k < 32; k += 8)
    out[(size_t)(bx + ty + k) * G_DIM + by + tx] = t[tx][ty + k];
}

// ---- pg-only deinterleave into X rows 0..2047 (gg rows written by softmax) ----
__global__ __launch_bounds__(384) void deinterleave_pg_k(const float* __restrict__ pg,
                                                         __bf16* __restrict__ X) {
  const int rr = blockIdx.x;  // 0..1023
  const float* src = pg + (size_t)rr * G_DIM * 2;
  const int t = threadIdx.x;
  const float4* s4 = (const float4*)(src + (size_t)t * 16);
  float4 a = s4[0], b = s4[1], c = s4[2], d = s4[3];
  bf16x8 v0, v1;
  v0[0] = (__bf16)a.x; v1[0] = (__bf16)a.y;
  v0[1] = (__bf16)a.z; v1[1] = (__bf16)a.w;
  v0[2] = (__bf16)b.x; v1[2] = (__bf16)b.y;
  v0[3] = (__bf16)b.z; v1[3] = (__bf16)b.w;
  v0[4] = (__bf16)c.x; v1[4] = (__bf16)c.y;
  v0[5] = (__bf16)c.z; v1[5] = (__bf16)c.w;
  v0[6] = (__bf16)d.x; v1[6] = (__bf16)d.y;
  v0[7] = (__bf16)d.z; v1[7] = (__bf16)d.w;
  *(bf16x8*)(X + (size_t)(rr * 2) * G_DIM + t * 8)     = v0;
  *(bf16x8*)(X + (size_t)(rr * 2 + 1) * G_DIM + t * 8) = v1;
}

// ------- one staged global->LDS chunk (1 KiB), pre-swizzled source (rule #21) -------
__device__ __forceinline__ void stage1(const __bf16* __restrict__ src, size_t row0,
                                       int K, int k0, char* ldsbase, int chunk, int lane) {
  int Lb = chunk << 10;                   // wave-uniform LDS byte base
  int L  = Lb + lane * 16;                // this lane's dest byte
  int r  = L >> 7;                        // region row
  int slot = ((L >> 4) & 7) ^ (r & 7);    // inverse swizzle on SOURCE
  const __bf16* g = src + (row0 + (size_t)r) * (size_t)K + (size_t)(k0 + slot * 8);
  __builtin_amdgcn_global_load_lds((const __attribute__((address_space(1))) void*)g,
                                   (__attribute__((address_space(3))) void*)(ldsbase + Lb),
                                   16, 0, 0);
}

#define MFMA16(a, b, c) __builtin_amdgcn_mfma_f32_16x16x32_bf16((a), (b), (c), 0, 0, 0)
#define LDS_RD(base, row, xx) (*(const bf16x8*)((base) + (size_t)(row) * 128 + (xx)))
#define LGKM0()  asm volatile("s_waitcnt lgkmcnt(0)" ::: "memory")
#define VM3()    asm volatile("s_waitcnt vmcnt(3)" ::: "memory")
#define VM0()    asm volatile("s_waitcnt vmcnt(0)" ::: "memory")
#define BAR()    __builtin_amdgcn_s_barrier()
#define PRIO(x)  __builtin_amdgcn_s_setprio(x)
#define FENCE()  asm volatile("" ::: "memory")

// ======== PROPAGATE: 256x192 NT GEMM, 3 phases / K-tile (R7/R9 proven, 162 us) ========
// 8 waves (2M x 4N), wave tile 128x48, acc[8][3]. LDS: 2 bufs x (A 32K | B 24K).
// out f32 paired = acc + 0.9*orig f32 (propagate, X row = rr*2+c)
__global__ __launch_bounds__(512, 2) void gemm3p(const __bf16* __restrict__ A,
                                                 const __bf16* __restrict__ B,
                                                 void* __restrict__ C,
                                                 const float* __restrict__ pgin,
                                                 const float* __restrict__ ggin,
                                                 int M, int N, int K) {
  __shared__ char lds[114688];   // 2 x (32 KiB A + 24 KiB B)

  const int tid = threadIdx.x;
  const int wave = tid >> 6, lane = tid & 63;
  const int wm = wave >> 2, wn = wave & 3;   // 2M x 4N
  const int lr = lane & 15, g4 = lane >> 4;

  const size_t arow0 = (size_t)blockIdx.x * 256;   // bx = M-tile
  const size_t brow0 = (size_t)blockIdx.y * 192;

  f32x4 acc[8][3] = {};
  const int NT = K / 64;

  const int a2w = wave * 2;
  const int b3w = wave * 3;
  const int x0 = ((g4) ^ (lr & 7)) * 16;
  const int x1 = ((4 + g4) ^ (lr & 7)) * 16;

  // prologue: tile0 {A0,A1,B} + tile1 {B}
  {
    char* b0 = lds;
    char* b1 = lds + 57344;
    stage1(A, arow0,       K, 0,  b0,         a2w, lane);
    stage1(A, arow0,       K, 0,  b0,         a2w + 1, lane);
    stage1(A, arow0 + 128, K, 0,  b0 + 16384, a2w, lane);
    stage1(A, arow0 + 128, K, 0,  b0 + 16384, a2w + 1, lane);
    stage1(B, brow0,       K, 0,  b0 + 32768, b3w, lane);
    stage1(B, brow0,       K, 0,  b0 + 32768, b3w + 1, lane);
    stage1(B, brow0,       K, 0,  b0 + 32768, b3w + 2, lane);
    stage1(B, brow0,       K, 64, b1 + 32768, b3w, lane);
    stage1(B, brow0,       K, 64, b1 + 32768, b3w + 1, lane);
    stage1(B, brow0,       K, 64, b1 + 32768, b3w + 2, lane);
  }
  VM3();
  BAR();

  for (int t = 0; t < NT; ++t) {
    char* buf = lds + (t & 1) * 57344;
    char* nxt = lds + ((t + 1) & 1) * 57344;
    char* Ab = buf + wm * 16384;
    char* Bb = buf + 32768;
    const int kn = (t + 1) * 64;
    const int k2 = (t + 2) * 64;
    const bool pa = (t + 1) < NT;
    const bool pb = (t + 2) < NT;

    bf16x8 alo[4][2], ahi[4][2], b01[2][2], b2[2];

    // ---- ph1: stage A0_{t+1}; read alo + b01; MFMA alo x b01 (16) ----
    if (pa) {
      stage1(A, arow0, K, kn, nxt, a2w, lane);
      stage1(A, arow0, K, kn, nxt, a2w + 1, lane);
    }
#pragma unroll
    for (int mf = 0; mf < 4; ++mf) {
      alo[mf][0] = LDS_RD(Ab, mf * 16 + lr, x0);
      alo[mf][1] = LDS_RD(Ab, mf * 16 + lr, x1);
    }
#pragma unroll
    for (int nf = 0; nf < 2; ++nf) {
      b01[nf][0] = LDS_RD(Bb, wn * 48 + nf * 16 + lr, x0);
      b01[nf][1] = LDS_RD(Bb, wn * 48 + nf * 16 + lr, x1);
    }
    PRIO(1);
#pragma unroll
    for (int mf = 0; mf < 4; ++mf)
#pragma unroll
      for (int nf = 0; nf < 2; ++nf)
#pragma unroll
        for (int ks = 0; ks < 2; ++ks)
          acc[mf][nf] = MFMA16(alo[mf][ks], b01[nf][ks], acc[mf][nf]);
    PRIO(0);

    // ---- ph2: stage A1_{t+1}; read ahi + b2; MFMA (alo,ahi) x b2 (16) ----
    if (pa) {
      stage1(A, arow0 + 128, K, kn, nxt + 16384, a2w, lane);
      stage1(A, arow0 + 128, K, kn, nxt + 16384, a2w + 1, lane);
    }
#pragma unroll
    for (int mf = 0; mf < 4; ++mf) {
      ahi[mf][0] = LDS_RD(Ab, 64 + mf * 16 + lr, x0);
      ahi[mf][1] = LDS_RD(Ab, 64 + mf * 16 + lr, x1);
    }
    b2[0] = LDS_RD(Bb, wn * 48 + 32 + lr, x0);
    b2[1] = LDS_RD(Bb, wn * 48 + 32 + lr, x1);
    PRIO(1);
#pragma unroll
    for (int mf = 0; mf < 4; ++mf)
#pragma unroll
      for (int ks = 0; ks < 2; ++ks) {
        acc[mf][2]     = MFMA16(alo[mf][ks], b2[ks], acc[mf][2]);
        acc[4 + mf][2] = MFMA16(ahi[mf][ks], b2[ks], acc[4 + mf][2]);
      }
    PRIO(0);
    LGKM0();
    BAR();     // BAR#1: safe to overwrite buf.B

    // ---- ph3: stage B_{t+2} -> buf; MFMA ahi x b01 (16); gate; BAR#2 ----
    if (pb) {
      stage1(B, brow0, K, k2, Bb, b3w, lane);
      stage1(B, brow0, K, k2, Bb, b3w + 1, lane);
      stage1(B, brow0, K, k2, Bb, b3w + 2, lane);
    }
    PRIO(1);
#pragma unroll
    for (int mf = 0; mf < 4; ++mf)
#pragma unroll
      for (int nf = 0; nf < 2; ++nf)
#pragma unroll
        for (int ks = 0; ks < 2; ++ks)
          acc[4 + mf][nf] = MFMA16(ahi[mf][ks], b01[nf][ks], acc[4 + mf][nf]);
    PRIO(0);
    if (t >= NT - 2) VM0(); else VM3();
    BAR();     // BAR#2
  }

  // epilogue — C/D layout: col = lane&15, row = (lane>>4)*4 + reg
  const int r0 = (int)arow0 + wm * 128;
  const int c0 = (int)brow0 + wn * 48;
#pragma unroll
  for (int mf = 0; mf < 8; ++mf) {
#pragma unroll
    for (int nf = 0; nf < 3; ++nf) {
      const int col = c0 + nf * 16 + lr;
#pragma unroll
      for (int jp = 0; jp < 2; ++jp) {
        const int row = r0 + mf * 16 + g4 * 4 + jp * 2;  // even
        const int rr = row >> 1;
        const size_t base = (size_t)rr * G_DIM * 2 + (size_t)col * 2;
        const float* src = (rr < P_DIM) ? (pgin + base)
                                        : (ggin + base - (size_t)P_DIM * G_DIM * 2);
        float2 sv = *(const float2*)src;
        float2 ov;
        ov.x = acc[mf][nf][jp * 2]     + 0.9f * sv.x;
        ov.y = acc[mf][nf][jp * 2 + 1] + 0.9f * sv.y;
        *(float2*)((float*)C + base) = ov;
      }
    }
  }
  (void)M;
}

// ======== W-GEMM: 192x192 NT, one barrier / K-tile, A dbuf + B ring-3 (R8) ========
// grid 16x16 = 256 blocks = exactly 1 CU round. MF=6: wave tile 96x48.
// C bf16 = 0.9*(acc + e0[i,j])   (W = 0.9*(S^2 + S))
__global__ __launch_bounds__(512, 2) void gemmW(const __bf16* __restrict__ A,
                                                const __bf16* __restrict__ B,
                                                __bf16* __restrict__ C,
                                                const __bf16* __restrict__ e0,
                                                int N, int K) {
  constexpr int MF     = 6;
  constexpr int BM     = MF * 32;       // 192
  constexpr int ABYTES = BM * 128;      // 24576
  constexpr int ACH    = BM / 64;       // 3
  __shared__ char lds[2 * ABYTES + 3 * 24576];

  const int tid = threadIdx.x;
  const int wave = tid >> 6, lane = tid & 63;
  const int wm = wave >> 2, wn = wave & 3;   // 2M x 4N
  const int lr = lane & 15, g4 = lane >> 4;

  const size_t arow0 = (size_t)blockIdx.x * BM;
  const size_t brow0 = (size_t)blockIdx.y * 192;

  f32x4 acc[MF][3] = {};
  const int NT = K / 64;

  const int x0 = ((g4) ^ (lr & 7)) * 16;
  const int x1 = ((4 + g4) ^ (lr & 7)) * 16;
  const int arbase = wm * (MF * 16);

  {
    char* A0 = lds;
    char* B0 = lds + 2 * ABYTES;
    char* B1 = B0 + 24576;
#pragma unroll
    for (int q = 0; q < ACH; ++q) stage1(A, arow0, K, 0,  A0, wave * ACH + q, lane);
#pragma unroll
    for (int q = 0; q < 3; ++q)   stage1(B, brow0, K, 0,  B0, wave * 3 + q, lane);
#pragma unroll
    for (int q = 0; q < 3; ++q)   stage1(B, brow0, K, 64, B1, wave * 3 + q, lane);
  }

  for (int t = 0; t < NT; ++t) {
    char* Abuf = lds + (t & 1) * ABYTES;
    char* Anxt = lds + ((t + 1) & 1) * ABYTES;
    char* Bbuf = lds + 2 * ABYTES + (t % 3) * 24576;
    char* Bst  = lds + 2 * ABYTES + ((t + 2) % 3) * 24576;

    if (t == NT - 1) VM0(); else VM3();
    BAR();
    FENCE();

    if (t + 1 < NT) {
#pragma unroll
      for (int q = 0; q < ACH; ++q)
        stage1(A, arow0, K, (t + 1) * 64, Anxt, wave * ACH + q, lane);
    }
    if (t + 2 < NT) {
#pragma unroll
      for (int q = 0; q < 3; ++q)
        stage1(B, brow0, K, (t + 2) * 64, Bst, wave * 3 + q, lane);
    }

    bf16x8 av[MF][2], bv[3][2];
#pragma unroll
    for (int mf = 0; mf < MF; ++mf) {
      av[mf][0] = LDS_RD(Abuf, arbase + mf * 16 + lr, x0);
      av[mf][1] = LDS_RD(Abuf, arbase + mf * 16 + lr, x1);
    }
#pragma unroll
    for (int nf = 0; nf < 3; ++nf) {
      bv[nf][0] = LDS_RD(Bbuf, wn * 48 + nf * 16 + lr, x0);
      bv[nf][1] = LDS_RD(Bbuf, wn * 48 + nf * 16 + lr, x1);
    }
    PRIO(1);
#pragma unroll
    for (int mf = 0; mf < MF; ++mf)
#pragma unroll
      for (int nf = 0; nf < 3; ++nf)
#pragma unroll
        for (int ks = 0; ks < 2; ++ks)
          acc[mf][nf] = MFMA16(av[mf][ks], bv[nf][ks], acc[mf][nf]);
    PRIO(0);
    LGKM0();
  }

  const int r0 = (int)arow0 + arbase;
  const int c0 = (int)brow0 + wn * 48;
#pragma unroll
  for (int mf = 0; mf < MF; ++mf) {
#pragma unroll
    for (int nf = 0; nf < 3; ++nf) {
      const int col = c0 + nf * 16 + lr;
#pragma unroll
      for (int jj = 0; jj < 4; ++jj) {
        const int row = r0 + mf * 16 + g4 * 4 + jj;
        float w = 0.9f * (acc[mf][nf][jj] + (float)e0[(size_t)row * N + col]);
        C[(size_t)row * N + col] = (__bf16)w;
      }
    }
  }
}

// ---------------- launch ----------------
extern "C" void kernel_launch(void* const* d_in, const int* in_sizes, int n_in,
                              void* d_out, int out_size, void* d_ws, size_t ws_size,
                              hipStream_t stream) {
  const float* pg = (const float*)d_in[0];  // [P,G,2] f32
  const float* gg = (const float*)d_in[1];  // [G,G,2] f32
  float* out = (float*)d_out;

  char* ws = (char*)d_ws;
  __bf16* X  = (__bf16*)ws;                        // [0, 50.3M)
  __bf16* W  = (__bf16*)(ws + XBYTES);             // [50.3M, 69.2M)
  // d_out doubles as scratch until the propagate overwrites every element:
  __bf16* S  = (__bf16*)d_out;                     // d_out [0, 18.9M)
  __bf16* St = (__bf16*)((char*)d_out + GG2);      // d_out [18.9M, 37.7M)

  // 1. S = alpha*softmax(gg ch1, -inf diag); ALSO writes X gg-rows (fused)
  row_softmax_k<<<G_DIM, 256, 0, stream>>>(gg, S, X);
  // 2. St = S^T
  transpose_k<<<dim3(96, 96), dim3(32, 8), 0, stream>>>(S, St);
  // 3. W = 0.9*(S*S + S)   (192x192 tile -> 256 blocks = exactly 1 CU round)
  gemmW<<<dim3(16, 16), 512, 0, stream>>>(S, St, W, S, G_DIM, G_DIM);
  // 4. X pg-rows only (gg rows already written by softmax)
  deinterleave_pg_k<<<P_DIM, 384, 0, stream>>>(pg, X);
  // 5. out = X * W^T + 0.9 * X_f32  (overwrites the S/St scratch in d_out)
  gemm3p<<<dim3(32, 16), 512, 0, stream>>>(X, W, out, pg, gg, 8192, G_DIM, G_DIM);
  (void)in_sizes; (void)n_in; (void)out_size; (void)ws_size;
}